// Round 8
// baseline (550.598 us; speedup 1.0000x reference)
//
#include <hip/hip_runtime.h>
#include <cmath>

#define T_SIZE (1u << 19)

typedef _Float16 h8 __attribute__((ext_vector_type(8)));
typedef _Float16 h4 __attribute__((ext_vector_type(4)));
typedef _Float16 h2 __attribute__((ext_vector_type(2)));
typedef float f4 __attribute__((ext_vector_type(4)));

struct Levels {
    float scale[16];
    int   res[16];
    unsigned dense_mask;
};

// softplus(10z)/10, branch-free
__device__ __forceinline__ float softplus10(float z) {
    float e = __builtin_amdgcn_exp2f(fminf(z * 14.426950408889634f, 126.0f)); // e^{10z}
    return __builtin_amdgcn_logf(1.0f + e) * 0.069314718055994531f;
}

// -------- Kernel 0a: table f32 -> f16 (4 entries / thread) ----
__global__ __launch_bounds__(256) void convert_table_kernel(
    const float2* __restrict__ t, h2* __restrict__ o, int total4)
{
    int i = blockIdx.x * 256 + threadIdx.x;
    if (i >= total4) return;
    const float2* src = t + (size_t)i * 4;
    h8 r;
#pragma unroll
    for (int j = 0; j < 4; ++j) {
        float2 v = src[j];
        r[2 * j]     = (_Float16)v.x;
        r[2 * j + 1] = (_Float16)v.y;
    }
    *(h8*)(o + (size_t)i * 4) = r;
}

// -------- Kernel 0b: weights f32 -> f16 (w1|w2|w3 concat: 2048|4096|4096) ----
__global__ __launch_bounds__(256) void convert_weights_kernel(
    const float* __restrict__ w1, const float* __restrict__ w2,
    const float* __restrict__ w3, _Float16* __restrict__ o)
{
    int i = blockIdx.x * 256 + threadIdx.x;   // grid 40*256 = 10240 exactly
    float v;
    if (i < 2048)      v = w1[i];
    else if (i < 6144) v = w2[i - 2048];
    else               v = w3[i - 6144];
    o[i] = (_Float16)v;
}

// ---------------- Kernel A: hash-grid encode ----------------
// Output layout enc3: [4 level-groups][N points][16B = 4 levels x h2].
// blockIdx.y = level (slow-varying) keeps 1-2 levels hot -> table L2-resident.
// Aligned 8B pair loads (x-corners differ by ^1 hash / +1 dense) minimize the
// divergent-address count — the measured limiter (~2.4 cyc per miss-transaction).
__global__ __launch_bounds__(256) void encode_kernel(
    const float* __restrict__ xs, const h2* __restrict__ table,
    char* __restrict__ enc3, Levels lv, int N)
{
    __shared__ float sx[768];
    __shared__ float s_scale[16];
    __shared__ int   s_res[16];

    const int i0 = blockIdx.x * 256;
    for (int t = threadIdx.x; t < 768; t += 256) sx[t] = xs[(size_t)i0 * 3 + t];
    if (threadIdx.x < 16) {
        s_scale[threadIdx.x] = lv.scale[threadIdx.x];
        s_res[threadIdx.x]   = lv.res[threadIdx.x];
    }
    __syncthreads();

    const int l = blockIdx.y;
    const int i = i0 + threadIdx.x;
    if (i >= N) return;

    const float px = sx[threadIdx.x * 3 + 0];
    const float py = sx[threadIdx.x * 3 + 1];
    const float pz = sx[threadIdx.x * 3 + 2];
    const float s  = s_scale[l];
    const int  res = s_res[l];

    float fx = px * s + 0.5f, fy = py * s + 0.5f, fz = pz * s + 0.5f;
    float gx = floorf(fx), gy = floorf(fy), gz = floorf(fz);
    float wx = fx - gx, wy = fy - gy, wz = fz - gz;
    int cx = (int)gx, cy = (int)gy, cz = (int)gz;

    const h2* tl = table + (size_t)l * T_SIZE;
    float2 vx0[4], vx1[4];             // combo j: y=(j>>1), z=(j&1)

    if ((lv.dense_mask >> l) & 1u) {   // uniform branch
        int r1 = res - 1;
        int x0 = min(cx, r1), x1 = min(cx + 1, r1);
        int y0 = min(cy, r1), y1 = min(cy + 1, r1);
        int z0 = min(cz, r1), z1 = min(cz + 1, r1);
        int rr = res * res;
        int bases[4] = {y0 * res + z0 * rr, y0 * res + z1 * rr,
                        y1 * res + z0 * rr, y1 * res + z1 * rr};
#pragma unroll
        for (int j = 0; j < 4; ++j) {
            int idx0 = x0 + bases[j];
            int idx1 = x1 + bases[j];
            h4 pr = *(const h4*)(tl + (idx0 & ~1));   // aligned 8B pair
            float2 lo = make_float2((float)pr[0], (float)pr[1]);
            float2 hi = make_float2((float)pr[2], (float)pr[3]);
            bool hi0 = idx0 & 1;
            vx0[j] = hi0 ? hi : lo;
            if (hi0 && idx1 != idx0) {
                h2 v = tl[idx1];
                vx1[j] = make_float2((float)v[0], (float)v[1]);
            } else {
                vx1[j] = (idx1 == idx0) ? vx0[j] : hi;
            }
        }
    } else {
        unsigned hy0 = (unsigned)cy * 2654435761u, hy1 = (unsigned)(cy + 1) * 2654435761u;
        unsigned hz0 = (unsigned)cz * 805459861u,  hz1 = (unsigned)(cz + 1) * 805459861u;
        unsigned Y[4] = {hy0 ^ hz0, hy0 ^ hz1, hy1 ^ hz0, hy1 ^ hz1};
        const bool odd = (cx & 1);
        const unsigned M = T_SIZE - 1;
#pragma unroll
        for (int j = 0; j < 4; ++j) {
            unsigned h0m = ((unsigned)cx ^ Y[j]) & M;
            unsigned h1m = ((unsigned)(cx + 1) ^ Y[j]) & M;
            h4 pr = *(const h4*)(tl + (h0m & ~1u));   // aligned 8B pair
            float2 lo = make_float2((float)pr[0], (float)pr[1]);
            float2 hi = make_float2((float)pr[2], (float)pr[3]);
            bool h0hi = (h0m & 1u);
            vx0[j] = h0hi ? hi : lo;
            if (odd) {
                h2 v = tl[h1m];
                vx1[j] = make_float2((float)v[0], (float)v[1]);
            } else {
                vx1[j] = h0hi ? lo : hi;              // even cx: h1m = h0m ^ 1
            }
        }
    }

    float wx0 = 1.f - wx, wy0 = 1.f - wy, wz0 = 1.f - wz;
    float wyz[4] = {wy0 * wz0, wy0 * wz, wy * wz0, wy * wz};
    float f0 = 0.f, f1 = 0.f;
#pragma unroll
    for (int j = 0; j < 4; ++j) {
        float w0 = wx0 * wyz[j], w1 = wx * wyz[j];
        f0 += w0 * vx0[j].x + w1 * vx1[j].x;
        f1 += w0 * vx0[j].y + w1 * vx1[j].y;
    }

    h2 r;
    r[0] = (_Float16)f0;
    r[1] = (_Float16)f1;
    // [group l>>2][point i][slot l&3], 16B per (group,point)
    *(h2*)(enc3 + (((size_t)(l >> 2) * N + i) << 4) + ((l & 3) << 2)) = r;
}

// generic 8-half fragment load (f16 direct dwordx4, or f32 + convert)
template <typename WT>
__device__ __forceinline__ h8 load_frag8(const WT* p) {
    if constexpr (sizeof(WT) == 2) {
        return *(const h8*)p;
    } else {
        h8 r;
#pragma unroll
        for (int j = 0; j < 8; ++j) r[j] = (_Float16)p[j];
        return r;
    }
}

// ---------------- Kernel B: fused MLP, operand-swapped MFMA ----------------
// D = W · act^T per layer. Latency-bound fix (R7 post-mortem): only aW1 + w4
// stay pinned; aW2/aW3 reloaded per tile-iter as h8 dwordx4 frags from the
// pre-converted f16 weight copy (asm barriers stop LICM from re-pinning) ->
// VGPR <= 128 -> 4 blocks/CU = 16 waves/CU (was 12, SIMDs 34% busy).
// enc3 pack: layer-1 B-frag is ONE 16B load. Layer 4 fused into layer-3
// register epilogue (w4-weighted softplus dot + shfl_xor reduce).
// A[m=lane&15][k=quad*8+j]; B[k=quad*8+j][n=lane&15]; D[row=quad*4+r][col=lane&15].
template <typename WT>
__global__ __launch_bounds__(256, 4) void mlp_kernel(
    const char* __restrict__ enc3,
    const WT* __restrict__ w1, const WT* __restrict__ w2,
    const WT* __restrict__ w3, const float* __restrict__ w4,
    float* __restrict__ out, int N)
{
    constexpr int AR = 72;                              // 144B rows, 16B-aligned
    __shared__ __align__(16) _Float16 sAct[256 * AR];   // 36864B -> 4 blocks/CU

    const int tid = threadIdx.x;
    const int wave = tid >> 6;
    const int lane = tid & 63;
    const int lrow = lane & 15;
    const int quad = lane >> 4;
    const int waveRow = wave * 64;
    const f4 zero = {0.f, 0.f, 0.f, 0.f};

    // pinned: layer-1 weights (16 VGPR) + packed w4 (8 VGPR)
    h8 aW1[4];
#pragma unroll
    for (int tm = 0; tm < 4; ++tm)
        aW1[tm] = load_frag8(w1 + (tm * 16 + lrow) * 32 + quad * 8);
    h4 w4q[4];
#pragma unroll
    for (int tm = 0; tm < 4; ++tm) {
        h4 t;
#pragma unroll
        for (int r = 0; r < 4; ++r) t[r] = (_Float16)w4[tm * 16 + quad * 4 + r];
        w4q[tm] = t;
    }

#pragma unroll 1
    for (int it = 0; it < 4; ++it) {
        asm volatile("" ::: "memory");   // stop LICM pinning the weight reloads
        h8 aW2[4][2];
#pragma unroll
        for (int tm = 0; tm < 4; ++tm)
#pragma unroll
            for (int km = 0; km < 2; ++km)
                aW2[tm][km] = load_frag8(w2 + (tm * 16 + lrow) * 64 + km * 32 + quad * 8);

        const int blockPt = (blockIdx.x * 4 + it) * 256;

        // ---- Layer 1: D1 = W1 · enc^T (one 16B B-frag load) ----
#pragma unroll
        for (int t = 0; t < 4; ++t) {
            const int ptg = blockPt + waveRow + t * 16 + lrow;
            h8 b = *(const h8*)(enc3 + (((size_t)quad * N + ptg) << 4));
            const int arow = (waveRow + t * 16 + lrow) * AR;
#pragma unroll
            for (int tm = 0; tm < 4; ++tm) {
                f4 acc = __builtin_amdgcn_mfma_f32_16x16x32_f16(aW1[tm], b, zero, 0, 0, 0);
                h4 pk;
#pragma unroll
                for (int r = 0; r < 4; ++r) pk[r] = (_Float16)softplus10(acc[r]);
                *(h4*)&sAct[arow + tm * 16 + quad * 4] = pk;     // 8B write
            }
        }
        // no barriers: wave-private rows, same-wave LDS ops are ordered

        // ---- Layer 2: D2 = W2 · act1^T ----
#pragma unroll
        for (int t = 0; t < 4; ++t) {
            const int arow = (waveRow + t * 16 + lrow) * AR;
            h8 b0 = *(const h8*)&sAct[arow + quad * 8];
            h8 b1 = *(const h8*)&sAct[arow + 32 + quad * 8];
            f4 accs[4];
#pragma unroll
            for (int tm = 0; tm < 4; ++tm) {
                f4 acc = __builtin_amdgcn_mfma_f32_16x16x32_f16(aW2[tm][0], b0, zero, 0, 0, 0);
                acc     = __builtin_amdgcn_mfma_f32_16x16x32_f16(aW2[tm][1], b1, acc,  0, 0, 0);
                accs[tm] = acc;
            }
#pragma unroll
            for (int tm = 0; tm < 4; ++tm) {
                h4 pk;
#pragma unroll
                for (int r = 0; r < 4; ++r) pk[r] = (_Float16)softplus10(accs[tm][r]);
                *(h4*)&sAct[arow + tm * 16 + quad * 4] = pk;
            }
        }

        asm volatile("" ::: "memory");   // aW3 loads stay here (after aW2 is dead)
        h8 aW3[4][2];
#pragma unroll
        for (int tm = 0; tm < 4; ++tm)
#pragma unroll
            for (int km = 0; km < 2; ++km)
                aW3[tm][km] = load_frag8(w3 + (tm * 16 + lrow) * 64 + km * 32 + quad * 8);

        // ---- Layer 3 + 4 fused: sdf = w4 · softplus(W3 · act2^T) ----
#pragma unroll
        for (int t = 0; t < 4; ++t) {
            const int arow = (waveRow + t * 16 + lrow) * AR;
            h8 b0 = *(const h8*)&sAct[arow + quad * 8];
            h8 b1 = *(const h8*)&sAct[arow + 32 + quad * 8];
            float sum = 0.f;
#pragma unroll
            for (int tm = 0; tm < 4; ++tm) {
                f4 acc = __builtin_amdgcn_mfma_f32_16x16x32_f16(aW3[tm][0], b0, zero, 0, 0, 0);
                acc     = __builtin_amdgcn_mfma_f32_16x16x32_f16(aW3[tm][1], b1, acc,  0, 0, 0);
#pragma unroll
                for (int r = 0; r < 4; ++r)
                    sum += (float)w4q[tm][r] * softplus10(acc[r]);
            }
            sum += __shfl_xor(sum, 16, 64);   // reduce across the 4 quads
            sum += __shfl_xor(sum, 32, 64);
            if (quad == 0)
                out[blockPt + waveRow + t * 16 + lrow] = sum;
        }
    }
}

// Fallback encode (f32 table) if workspace too small for f16 table
__global__ __launch_bounds__(256) void encode_kernel_f32(
    const float* __restrict__ xs, const float2* __restrict__ table,
    char* __restrict__ enc3, Levels lv, int N)
{
    const int i = blockIdx.x * 256 + threadIdx.x;
    const int l = blockIdx.y;
    if (i >= N) return;
    float px = xs[3 * i], py = xs[3 * i + 1], pz = xs[3 * i + 2];
    float s = lv.scale[l];
    int res = lv.res[l];
    float fx = px * s + 0.5f, fy = py * s + 0.5f, fz = pz * s + 0.5f;
    float gx = floorf(fx), gy = floorf(fy), gz = floorf(fz);
    float wx = fx - gx, wy = fy - gy, wz = fz - gz;
    int cx = (int)gx, cy = (int)gy, cz = (int)gz;
    unsigned idx[8];
    if ((lv.dense_mask >> l) & 1u) {
        int r1 = res - 1;
        int x0 = min(cx, r1), x1 = min(cx + 1, r1);
        int y0 = min(cy, r1), y1 = min(cy + 1, r1);
        int z0 = min(cz, r1), z1 = min(cz + 1, r1);
        int rr = res * res;
        idx[0] = x0 + y0 * res + z0 * rr; idx[1] = x0 + y0 * res + z1 * rr;
        idx[2] = x0 + y1 * res + z0 * rr; idx[3] = x0 + y1 * res + z1 * rr;
        idx[4] = x1 + y0 * res + z0 * rr; idx[5] = x1 + y0 * res + z1 * rr;
        idx[6] = x1 + y1 * res + z0 * rr; idx[7] = x1 + y1 * res + z1 * rr;
    } else {
        unsigned hx0 = (unsigned)cx, hx1 = (unsigned)(cx + 1);
        unsigned hy0 = (unsigned)cy * 2654435761u, hy1 = (unsigned)(cy + 1) * 2654435761u;
        unsigned hz0 = (unsigned)cz * 805459861u,  hz1 = (unsigned)(cz + 1) * 805459861u;
        idx[0] = (hx0^hy0^hz0) & (T_SIZE-1); idx[1] = (hx0^hy0^hz1) & (T_SIZE-1);
        idx[2] = (hx0^hy1^hz0) & (T_SIZE-1); idx[3] = (hx0^hy1^hz1) & (T_SIZE-1);
        idx[4] = (hx1^hy0^hz0) & (T_SIZE-1); idx[5] = (hx1^hy0^hz1) & (T_SIZE-1);
        idx[6] = (hx1^hy1^hz0) & (T_SIZE-1); idx[7] = (hx1^hy1^hz1) & (T_SIZE-1);
    }
    const float2* tl = table + (size_t)l * T_SIZE;
    float wx0 = 1.f - wx, wy0 = 1.f - wy, wz0 = 1.f - wz;
    float wcs[8] = {wx0*wy0*wz0, wx0*wy0*wz, wx0*wy*wz0, wx0*wy*wz,
                    wx*wy0*wz0,  wx*wy0*wz,  wx*wy*wz0,  wx*wy*wz};
    float f0 = 0.f, f1 = 0.f;
#pragma unroll
    for (int c = 0; c < 8; ++c) {
        float2 v = tl[idx[c]];
        f0 += wcs[c] * v.x; f1 += wcs[c] * v.y;
    }
    h2 r; r[0] = (_Float16)f0; r[1] = (_Float16)f1;
    *(h2*)(enc3 + (((size_t)(l >> 2) * N + i) << 4) + ((l & 3) << 2)) = r;
}

extern "C" void kernel_launch(void* const* d_in, const int* in_sizes, int n_in,
                              void* d_out, int out_size, void* d_ws, size_t ws_size,
                              hipStream_t stream) {
    const float* x     = (const float*)d_in[0];
    const float* table = (const float*)d_in[1];
    const float* w1    = (const float*)d_in[2];
    const float* w2    = (const float*)d_in[3];
    const float* w3    = (const float*)d_in[4];
    const float* w4    = (const float*)d_in[5];
    float* out = (float*)d_out;
    const int N = in_sizes[0] / 3;                 // 1<<20

    Levels lv;
    lv.dense_mask = 0;
    const double pls = exp2(log2(2048.0 / 16.0) / 15.0);
    const double lg  = log2(pls);
    for (int l = 0; l < 16; ++l) {
        double sc = exp2((double)l * lg) * 16.0 - 1.0;
        int res = (int)ceil(sc) + 1;
        lv.scale[l] = (float)sc;
        lv.res[l]   = res;
        if ((long long)res * res * res <= (long long)T_SIZE) lv.dense_mask |= (1u << l);
    }

    const size_t encBytes   = (size_t)16 * N * 4;        // 64 MB ([4][N][16B])
    const size_t tableBytes = (size_t)16 * T_SIZE * 4;   // 33.5 MB
    const size_t whBytes    = 32768;                     // 10240 f16 weights, padded
    char* enc3 = (char*)d_ws;

    const int ptBlocks = (N + 255) / 256;                // 4096
    dim3 encGrid(ptBlocks, 16);                          // y = level, slow-varying
    const int mlpBlocks = N / (256 * 4);                 // 1024, exactly 4 tiles each

    if (ws_size >= encBytes + tableBytes + whBytes) {
        h2* table16 = (h2*)((char*)d_ws + encBytes);
        _Float16* wh = (_Float16*)((char*)d_ws + encBytes + tableBytes);
        const int total4 = 16 * T_SIZE / 4;
        hipLaunchKernelGGL(convert_table_kernel, dim3((total4 + 255) / 256), dim3(256), 0,
                           stream, (const float2*)table, table16, total4);
        hipLaunchKernelGGL(convert_weights_kernel, dim3(40), dim3(256), 0, stream,
                           w1, w2, w3, wh);
        hipLaunchKernelGGL(encode_kernel, encGrid, dim3(256), 0, stream,
                           x, (const h2*)table16, enc3, lv, N);
        hipLaunchKernelGGL((mlp_kernel<_Float16>), dim3(mlpBlocks), dim3(256), 0, stream,
                           enc3, wh, wh + 2048, wh + 6144, w4, out, N);
    } else {
        hipLaunchKernelGGL(encode_kernel_f32, encGrid, dim3(256), 0, stream,
                           x, (const float2*)table, enc3, lv, N);
        hipLaunchKernelGGL((mlp_kernel<float>), dim3(mlpBlocks), dim3(256), 0, stream,
                           enc3, w1, w2, w3, w4, out, N);
    }
}

// Round 9
// 455.217 us; speedup vs baseline: 1.2095x; 1.2095x over previous
//
#include <hip/hip_runtime.h>
#include <cmath>

#define T_SIZE (1u << 19)

typedef _Float16 h8 __attribute__((ext_vector_type(8)));
typedef _Float16 h4 __attribute__((ext_vector_type(4)));
typedef _Float16 h2 __attribute__((ext_vector_type(2)));
typedef float f4 __attribute__((ext_vector_type(4)));

struct Levels {
    float scale[16];
    int   res[16];
    unsigned dense_mask;
};

// softplus(10z)/10, branch-free
__device__ __forceinline__ float softplus10(float z) {
    float e = __builtin_amdgcn_exp2f(fminf(z * 14.426950408889634f, 126.0f)); // e^{10z}
    return __builtin_amdgcn_logf(1.0f + e) * 0.069314718055994531f;
}

// -------- Kernel 0a: table f32 -> f16 (4 entries / thread) ----
__global__ __launch_bounds__(256) void convert_table_kernel(
    const float2* __restrict__ t, h2* __restrict__ o, int total4)
{
    int i = blockIdx.x * 256 + threadIdx.x;
    if (i >= total4) return;
    const float2* src = t + (size_t)i * 4;
    h8 r;
#pragma unroll
    for (int j = 0; j < 4; ++j) {
        float2 v = src[j];
        r[2 * j]     = (_Float16)v.x;
        r[2 * j + 1] = (_Float16)v.y;
    }
    *(h8*)(o + (size_t)i * 4) = r;
}

// -------- Kernel 0b: weights f32 -> f16 (w1|w2|w3 concat: 2048|4096|4096) ----
__global__ __launch_bounds__(256) void convert_weights_kernel(
    const float* __restrict__ w1, const float* __restrict__ w2,
    const float* __restrict__ w3, _Float16* __restrict__ o)
{
    int i = blockIdx.x * 256 + threadIdx.x;   // grid 40*256 = 10240 exactly
    float v;
    if (i < 2048)      v = w1[i];
    else if (i < 6144) v = w2[i - 2048];
    else               v = w3[i - 6144];
    o[i] = (_Float16)v;
}

// Two-corner gather from one aligned 16B 4-entry group when possible.
// i0's group always loaded as dwordx4; i1 is in the same group for ~3/4 of
// lanes (cx even -> i1=i0^1; cx%4==1 -> i1=i0^3; dense: i1=i0+{0,1} unless
// pos0==3). Out-of-group lanes do one masked 4B load.
__device__ __forceinline__ void gather_pair(
    const h2* __restrict__ tl, unsigned i0, unsigned i1,
    float2& v0, float2& v1)
{
    unsigned g = i0 & ~3u;
    union { h8 v; uint4 u; } cv;
    cv.v = *(const h8*)(tl + g);
    unsigned p0 = i0 & 3u;
    unsigned a01 = (p0 & 1u) ? cv.u.y : cv.u.x;
    unsigned a23 = (p0 & 1u) ? cv.u.w : cv.u.z;
    unsigned e0  = (p0 & 2u) ? a23 : a01;
    unsigned e1;
    if ((i1 & ~3u) == g) {
        unsigned p1 = i1 & 3u;
        unsigned b01 = (p1 & 1u) ? cv.u.y : cv.u.x;
        unsigned b23 = (p1 & 1u) ? cv.u.w : cv.u.z;
        e1 = (p1 & 2u) ? b23 : b01;
    } else {
        e1 = *(const unsigned*)(tl + i1);     // masked, ~1/4 of lanes
    }
    h2 c0 = __builtin_bit_cast(h2, e0);
    h2 c1 = __builtin_bit_cast(h2, e1);
    v0 = make_float2((float)c0[0], (float)c0[1]);
    v1 = make_float2((float)c1[0], (float)c1[1]);
}

// ---------------- Kernel A: hash-grid encode -> enc2 [16][N] h2 ----------------
// Launched 4x with lbase = 0,4,8,12 (4 levels per dispatch): keeps 1-2 levels
// hot in L2, surfaces per-level-group cost, and lets the MLP show in top-5.
__global__ __launch_bounds__(256) void encode_kernel(
    const float* __restrict__ xs, const h2* __restrict__ table,
    h2* __restrict__ enc2, Levels lv, int lbase, int N)
{
    __shared__ float sx[768];
    __shared__ float s_scale[16];
    __shared__ int   s_res[16];

    const int i0 = blockIdx.x * 256;
    for (int t = threadIdx.x; t < 768; t += 256) sx[t] = xs[(size_t)i0 * 3 + t];
    if (threadIdx.x < 16) {
        s_scale[threadIdx.x] = lv.scale[threadIdx.x];
        s_res[threadIdx.x]   = lv.res[threadIdx.x];
    }
    __syncthreads();

    const int l = lbase + blockIdx.y;
    const int i = i0 + threadIdx.x;
    if (i >= N) return;

    const float px = sx[threadIdx.x * 3 + 0];
    const float py = sx[threadIdx.x * 3 + 1];
    const float pz = sx[threadIdx.x * 3 + 2];
    const float s  = s_scale[l];
    const int  res = s_res[l];

    float fx = px * s + 0.5f, fy = py * s + 0.5f, fz = pz * s + 0.5f;
    float gx = floorf(fx), gy = floorf(fy), gz = floorf(fz);
    float wx = fx - gx, wy = fy - gy, wz = fz - gz;
    int cx = (int)gx, cy = (int)gy, cz = (int)gz;

    const h2* tl = table + (size_t)l * T_SIZE;
    float2 vx0[4], vx1[4];             // combo j: y=(j>>1), z=(j&1)

    if ((lv.dense_mask >> l) & 1u) {   // uniform branch
        int r1 = res - 1;
        int x0 = min(cx, r1), x1 = min(cx + 1, r1);
        int y0 = min(cy, r1), y1 = min(cy + 1, r1);
        int z0 = min(cz, r1), z1 = min(cz + 1, r1);
        int rr = res * res;
        int bases[4] = {y0 * res + z0 * rr, y0 * res + z1 * rr,
                        y1 * res + z0 * rr, y1 * res + z1 * rr};
#pragma unroll
        for (int j = 0; j < 4; ++j)
            gather_pair(tl, (unsigned)(x0 + bases[j]), (unsigned)(x1 + bases[j]),
                        vx0[j], vx1[j]);
    } else {
        unsigned hy0 = (unsigned)cy * 2654435761u, hy1 = (unsigned)(cy + 1) * 2654435761u;
        unsigned hz0 = (unsigned)cz * 805459861u,  hz1 = (unsigned)(cz + 1) * 805459861u;
        unsigned Y[4] = {hy0 ^ hz0, hy0 ^ hz1, hy1 ^ hz0, hy1 ^ hz1};
        const unsigned M = T_SIZE - 1;
#pragma unroll
        for (int j = 0; j < 4; ++j)
            gather_pair(tl, ((unsigned)cx ^ Y[j]) & M,
                        ((unsigned)(cx + 1) ^ Y[j]) & M, vx0[j], vx1[j]);
    }

    float wx0 = 1.f - wx, wy0 = 1.f - wy, wz0 = 1.f - wz;
    float wyz[4] = {wy0 * wz0, wy0 * wz, wy * wz0, wy * wz};
    float f0 = 0.f, f1 = 0.f;
#pragma unroll
    for (int j = 0; j < 4; ++j) {
        float w0 = wx0 * wyz[j], w1 = wx * wyz[j];
        f0 += w0 * vx0[j].x + w1 * vx1[j].x;
        f1 += w0 * vx0[j].y + w1 * vx1[j].y;
    }

    h2 r;
    r[0] = (_Float16)f0;
    r[1] = (_Float16)f1;
    enc2[(size_t)l * N + i] = r;       // coalesced 4B store
}

// generic 8-half fragment load (f16 direct dwordx4, or f32 + convert)
template <typename WT>
__device__ __forceinline__ h8 load_frag8(const WT* p) {
    if constexpr (sizeof(WT) == 2) {
        return *(const h8*)p;
    } else {
        h8 r;
#pragma unroll
        for (int j = 0; j < 8; ++j) r[j] = (_Float16)p[j];
        return r;
    }
}

// ---------------- Kernel B: fused MLP, operand-swapped MFMA (R7 struct) -------
// D = W · act^T per layer: A = pinned weight frags, B = activation frags.
// Layer 4 fused into layer-3 register epilogue (w4 dot + shfl_xor reduce).
// LB(256,3): 170-VGPR cap fits all pinned frags without spills.
// A[m=lane&15][k=quad*8+j]; B[k=quad*8+j][n=lane&15]; D[row=quad*4+r][col=lane&15].
template <typename WT>
__global__ __launch_bounds__(256, 3) void mlp_kernel(
    const h2* __restrict__ enc2,
    const WT* __restrict__ w1, const WT* __restrict__ w2,
    const WT* __restrict__ w3, const float* __restrict__ w4,
    float* __restrict__ out, int nTiles, int N)
{
    constexpr int AR = 72;                              // 144B rows, 16B-aligned
    __shared__ __align__(16) _Float16 sAct[256 * AR];   // 36864B

    const int tid = threadIdx.x;
    const int wave = tid >> 6;
    const int lane = tid & 63;
    const int lrow = lane & 15;
    const int quad = lane >> 4;
    const int waveRow = wave * 64;
    const f4 zero = {0.f, 0.f, 0.f, 0.f};

    h8 aW1[4];
#pragma unroll
    for (int tm = 0; tm < 4; ++tm)
        aW1[tm] = load_frag8(w1 + (tm * 16 + lrow) * 32 + quad * 8);
    h8 aW2[4][2], aW3[4][2];
#pragma unroll
    for (int tm = 0; tm < 4; ++tm)
#pragma unroll
        for (int km = 0; km < 2; ++km) {
            aW2[tm][km] = load_frag8(w2 + (tm * 16 + lrow) * 64 + km * 32 + quad * 8);
            aW3[tm][km] = load_frag8(w3 + (tm * 16 + lrow) * 64 + km * 32 + quad * 8);
        }
    float w4f[16];
#pragma unroll
    for (int tm = 0; tm < 4; ++tm)
#pragma unroll
        for (int r = 0; r < 4; ++r)
            w4f[tm * 4 + r] = w4[tm * 16 + quad * 4 + r];

    for (int tile = blockIdx.x; tile < nTiles; tile += gridDim.x) {
        const int blockPt = tile * 256;

        // ---- Layer 1: D1 = W1 · enc^T ----
#pragma unroll
        for (int t = 0; t < 4; ++t) {
            const int ptg = blockPt + waveRow + t * 16 + lrow;
            h8 b;
#pragma unroll
            for (int d = 0; d < 4; ++d) {
                h2 p = enc2[(size_t)(quad * 4 + d) * N + ptg];   // 4B coalesced
                b[2 * d]     = p[0];
                b[2 * d + 1] = p[1];
            }
            const int arow = (waveRow + t * 16 + lrow) * AR;
#pragma unroll
            for (int tm = 0; tm < 4; ++tm) {
                f4 acc = __builtin_amdgcn_mfma_f32_16x16x32_f16(aW1[tm], b, zero, 0, 0, 0);
                h4 pk;
#pragma unroll
                for (int r = 0; r < 4; ++r) pk[r] = (_Float16)softplus10(acc[r]);
                *(h4*)&sAct[arow + tm * 16 + quad * 4] = pk;     // 8B write
            }
        }
        // no barriers: wave-private rows, same-wave LDS ops are ordered

        // ---- Layer 2: D2 = W2 · act1^T ----
#pragma unroll
        for (int t = 0; t < 4; ++t) {
            const int arow = (waveRow + t * 16 + lrow) * AR;
            h8 b0 = *(const h8*)&sAct[arow + quad * 8];
            h8 b1 = *(const h8*)&sAct[arow + 32 + quad * 8];
            f4 accs[4];
#pragma unroll
            for (int tm = 0; tm < 4; ++tm) {
                f4 acc = __builtin_amdgcn_mfma_f32_16x16x32_f16(aW2[tm][0], b0, zero, 0, 0, 0);
                acc     = __builtin_amdgcn_mfma_f32_16x16x32_f16(aW2[tm][1], b1, acc,  0, 0, 0);
                accs[tm] = acc;
            }
#pragma unroll
            for (int tm = 0; tm < 4; ++tm) {
                h4 pk;
#pragma unroll
                for (int r = 0; r < 4; ++r) pk[r] = (_Float16)softplus10(accs[tm][r]);
                *(h4*)&sAct[arow + tm * 16 + quad * 4] = pk;
            }
        }

        // ---- Layer 3 + 4 fused: sdf = w4 · softplus(W3 · act2^T) ----
#pragma unroll
        for (int t = 0; t < 4; ++t) {
            const int arow = (waveRow + t * 16 + lrow) * AR;
            h8 b0 = *(const h8*)&sAct[arow + quad * 8];
            h8 b1 = *(const h8*)&sAct[arow + 32 + quad * 8];
            float sum = 0.f;
#pragma unroll
            for (int tm = 0; tm < 4; ++tm) {
                f4 acc = __builtin_amdgcn_mfma_f32_16x16x32_f16(aW3[tm][0], b0, zero, 0, 0, 0);
                acc     = __builtin_amdgcn_mfma_f32_16x16x32_f16(aW3[tm][1], b1, acc,  0, 0, 0);
#pragma unroll
                for (int r = 0; r < 4; ++r)
                    sum += w4f[tm * 4 + r] * softplus10(acc[r]);
            }
            sum += __shfl_xor(sum, 16, 64);   // reduce across the 4 quads
            sum += __shfl_xor(sum, 32, 64);
            if (quad == 0)
                out[blockPt + waveRow + t * 16 + lrow] = sum;
        }
    }
}

// Fallback encode (f32 table) if workspace too small for f16 table
__global__ __launch_bounds__(256) void encode_kernel_f32(
    const float* __restrict__ xs, const float2* __restrict__ table,
    h2* __restrict__ enc2, Levels lv, int N)
{
    const int i = blockIdx.x * 256 + threadIdx.x;
    const int l = blockIdx.y;
    if (i >= N) return;
    float px = xs[3 * i], py = xs[3 * i + 1], pz = xs[3 * i + 2];
    float s = lv.scale[l];
    int res = lv.res[l];
    float fx = px * s + 0.5f, fy = py * s + 0.5f, fz = pz * s + 0.5f;
    float gx = floorf(fx), gy = floorf(fy), gz = floorf(fz);
    float wx = fx - gx, wy = fy - gy, wz = fz - gz;
    int cx = (int)gx, cy = (int)gy, cz = (int)gz;
    unsigned idx[8];
    if ((lv.dense_mask >> l) & 1u) {
        int r1 = res - 1;
        int x0 = min(cx, r1), x1 = min(cx + 1, r1);
        int y0 = min(cy, r1), y1 = min(cy + 1, r1);
        int z0 = min(cz, r1), z1 = min(cz + 1, r1);
        int rr = res * res;
        idx[0] = x0 + y0 * res + z0 * rr; idx[1] = x0 + y0 * res + z1 * rr;
        idx[2] = x0 + y1 * res + z0 * rr; idx[3] = x0 + y1 * res + z1 * rr;
        idx[4] = x1 + y0 * res + z0 * rr; idx[5] = x1 + y0 * res + z1 * rr;
        idx[6] = x1 + y1 * res + z0 * rr; idx[7] = x1 + y1 * res + z1 * rr;
    } else {
        unsigned hx0 = (unsigned)cx, hx1 = (unsigned)(cx + 1);
        unsigned hy0 = (unsigned)cy * 2654435761u, hy1 = (unsigned)(cy + 1) * 2654435761u;
        unsigned hz0 = (unsigned)cz * 805459861u,  hz1 = (unsigned)(cz + 1) * 805459861u;
        idx[0] = (hx0^hy0^hz0) & (T_SIZE-1); idx[1] = (hx0^hy0^hz1) & (T_SIZE-1);
        idx[2] = (hx0^hy1^hz0) & (T_SIZE-1); idx[3] = (hx0^hy1^hz1) & (T_SIZE-1);
        idx[4] = (hx1^hy0^hz0) & (T_SIZE-1); idx[5] = (hx1^hy0^hz1) & (T_SIZE-1);
        idx[6] = (hx1^hy1^hz0) & (T_SIZE-1); idx[7] = (hx1^hy1^hz1) & (T_SIZE-1);
    }
    const float2* tl = table + (size_t)l * T_SIZE;
    float wx0 = 1.f - wx, wy0 = 1.f - wy, wz0 = 1.f - wz;
    float wcs[8] = {wx0*wy0*wz0, wx0*wy0*wz, wx0*wy*wz0, wx0*wy*wz,
                    wx*wy0*wz0,  wx*wy0*wz,  wx*wy*wz0,  wx*wy*wz};
    float f0 = 0.f, f1 = 0.f;
#pragma unroll
    for (int c = 0; c < 8; ++c) {
        float2 v = tl[idx[c]];
        f0 += wcs[c] * v.x; f1 += wcs[c] * v.y;
    }
    h2 r; r[0] = (_Float16)f0; r[1] = (_Float16)f1;
    enc2[(size_t)l * N + i] = r;
}

extern "C" void kernel_launch(void* const* d_in, const int* in_sizes, int n_in,
                              void* d_out, int out_size, void* d_ws, size_t ws_size,
                              hipStream_t stream) {
    const float* x     = (const float*)d_in[0];
    const float* table = (const float*)d_in[1];
    const float* w1    = (const float*)d_in[2];
    const float* w2    = (const float*)d_in[3];
    const float* w3    = (const float*)d_in[4];
    const float* w4    = (const float*)d_in[5];
    float* out = (float*)d_out;
    const int N = in_sizes[0] / 3;                 // 1<<20

    Levels lv;
    lv.dense_mask = 0;
    const double pls = exp2(log2(2048.0 / 16.0) / 15.0);
    const double lg  = log2(pls);
    for (int l = 0; l < 16; ++l) {
        double sc = exp2((double)l * lg) * 16.0 - 1.0;
        int res = (int)ceil(sc) + 1;
        lv.scale[l] = (float)sc;
        lv.res[l]   = res;
        if ((long long)res * res * res <= (long long)T_SIZE) lv.dense_mask |= (1u << l);
    }

    const size_t encBytes   = (size_t)16 * N * 4;        // 64 MB ([16][N] h2)
    const size_t tableBytes = (size_t)16 * T_SIZE * 4;   // 33.5 MB
    const size_t whBytes    = 32768;                     // 10240 f16 weights
    h2* enc2 = (h2*)d_ws;

    const int ptBlocks = (N + 255) / 256;                // 4096
    const int nTiles = N / 256;                          // 4096
    const int mlpBlocks = 768;                           // 3 blocks/CU, grid-stride

    if (ws_size >= encBytes + tableBytes + whBytes) {
        h2* table16 = (h2*)((char*)d_ws + encBytes);
        _Float16* wh = (_Float16*)((char*)d_ws + encBytes + tableBytes);
        const int total4 = 16 * T_SIZE / 4;
        hipLaunchKernelGGL(convert_table_kernel, dim3((total4 + 255) / 256), dim3(256), 0,
                           stream, (const float2*)table, table16, total4);
        hipLaunchKernelGGL(convert_weights_kernel, dim3(40), dim3(256), 0, stream,
                           w1, w2, w3, wh);
        for (int lbase = 0; lbase < 16; lbase += 4)      // 4 dispatches x 4 levels
            hipLaunchKernelGGL(encode_kernel, dim3(ptBlocks, 4), dim3(256), 0, stream,
                               x, (const h2*)table16, enc2, lv, lbase, N);
        hipLaunchKernelGGL((mlp_kernel<_Float16>), dim3(mlpBlocks), dim3(256), 0, stream,
                           enc2, wh, wh + 2048, wh + 6144, w4, out, nTiles, N);
    } else {
        hipLaunchKernelGGL(encode_kernel_f32, dim3(ptBlocks, 16), dim3(256), 0, stream,
                           x, (const float2*)table, enc2, lv, N);
        hipLaunchKernelGGL((mlp_kernel<float>), dim3(mlpBlocks), dim3(256), 0, stream,
                           enc2, w1, w2, w3, w4, out, nTiles, N);
    }
}

// Round 10
// 429.865 us; speedup vs baseline: 1.2809x; 1.0590x over previous
//
#include <hip/hip_runtime.h>
#include <cmath>

#define T_SIZE (1u << 19)

typedef _Float16 h8 __attribute__((ext_vector_type(8)));
typedef _Float16 h4 __attribute__((ext_vector_type(4)));
typedef _Float16 h2 __attribute__((ext_vector_type(2)));
typedef float f4 __attribute__((ext_vector_type(4)));

struct Levels {
    float scale[16];
    int   res[16];
    unsigned dense_mask;
};

// softplus(10z)/10, branch-free
__device__ __forceinline__ float softplus10(float z) {
    float e = __builtin_amdgcn_exp2f(fminf(z * 14.426950408889634f, 126.0f)); // e^{10z}
    return __builtin_amdgcn_logf(1.0f + e) * 0.069314718055994531f;
}

// -------- Kernel 0: table f32->f16 (4 entries/thread) + weights f32->f16 ----
__global__ __launch_bounds__(256) void convert_kernel(
    const float2* __restrict__ t, h2* __restrict__ o, int total4,
    const float* __restrict__ w1, const float* __restrict__ w2,
    const float* __restrict__ w3, _Float16* __restrict__ wh)
{
    int i = blockIdx.x * 256 + threadIdx.x;
    if (i < total4) {
        const float2* src = t + (size_t)i * 4;
        h8 r;
#pragma unroll
        for (int j = 0; j < 4; ++j) {
            float2 v = src[j];
            r[2 * j]     = (_Float16)v.x;
            r[2 * j + 1] = (_Float16)v.y;
        }
        *(h8*)(o + (size_t)i * 4) = r;
    } else {
        int k = i - total4;                    // 40 extra blocks: 10240 weights
        if (k < 10240) {
            float v = (k < 2048) ? w1[k] : (k < 6144) ? w2[k - 2048] : w3[k - 6144];
            wh[k] = (_Float16)v;
        }
    }
}

// Two-corner gather; one aligned 16B 4-entry group covers both x-corners for
// ~3/4 of lanes, masked 4B load for the rest (measured law: time ~ #requests).
__device__ __forceinline__ void gather_pair(
    const h2* __restrict__ tl, unsigned i0, unsigned i1,
    float2& v0, float2& v1)
{
    unsigned g = i0 & ~3u;
    union { h8 v; uint4 u; } cv;
    cv.v = *(const h8*)(tl + g);
    unsigned p0 = i0 & 3u;
    unsigned a01 = (p0 & 1u) ? cv.u.y : cv.u.x;
    unsigned a23 = (p0 & 1u) ? cv.u.w : cv.u.z;
    unsigned e0  = (p0 & 2u) ? a23 : a01;
    unsigned e1;
    if ((i1 & ~3u) == g) {
        unsigned p1 = i1 & 3u;
        unsigned b01 = (p1 & 1u) ? cv.u.y : cv.u.x;
        unsigned b23 = (p1 & 1u) ? cv.u.w : cv.u.z;
        e1 = (p1 & 2u) ? b23 : b01;
    } else {
        e1 = *(const unsigned*)(tl + i1);
    }
    h2 c0 = __builtin_bit_cast(h2, e0);
    h2 c1 = __builtin_bit_cast(h2, e1);
    v0 = make_float2((float)c0[0], (float)c0[1]);
    v1 = make_float2((float)c1[0], (float)c1[1]);
}

// full per-(point,level) encode -> packed h2 feature pair
__device__ __forceinline__ h2 encode_point(
    float px, float py, float pz, float s, int res, bool dense,
    const h2* __restrict__ tl)
{
    float fx = px * s + 0.5f, fy = py * s + 0.5f, fz = pz * s + 0.5f;
    float gx = floorf(fx), gy = floorf(fy), gz = floorf(fz);
    float wx = fx - gx, wy = fy - gy, wz = fz - gz;
    int cx = (int)gx, cy = (int)gy, cz = (int)gz;

    float2 vx0[4], vx1[4];             // combo j: y=(j>>1), z=(j&1)
    if (dense) {
        int r1 = res - 1;
        int x0 = min(cx, r1), x1 = min(cx + 1, r1);
        int y0 = min(cy, r1), y1 = min(cy + 1, r1);
        int z0 = min(cz, r1), z1 = min(cz + 1, r1);
        int rr = res * res;
        int bases[4] = {y0 * res + z0 * rr, y0 * res + z1 * rr,
                        y1 * res + z0 * rr, y1 * res + z1 * rr};
#pragma unroll
        for (int j = 0; j < 4; ++j)
            gather_pair(tl, (unsigned)(x0 + bases[j]), (unsigned)(x1 + bases[j]),
                        vx0[j], vx1[j]);
    } else {
        unsigned hy0 = (unsigned)cy * 2654435761u, hy1 = (unsigned)(cy + 1) * 2654435761u;
        unsigned hz0 = (unsigned)cz * 805459861u,  hz1 = (unsigned)(cz + 1) * 805459861u;
        unsigned Y[4] = {hy0 ^ hz0, hy0 ^ hz1, hy1 ^ hz0, hy1 ^ hz1};
        const unsigned M = T_SIZE - 1;
#pragma unroll
        for (int j = 0; j < 4; ++j)
            gather_pair(tl, ((unsigned)cx ^ Y[j]) & M,
                        ((unsigned)(cx + 1) ^ Y[j]) & M, vx0[j], vx1[j]);
    }

    float wx0 = 1.f - wx, wy0 = 1.f - wy, wz0 = 1.f - wz;
    float wyz[4] = {wy0 * wz0, wy0 * wz, wy * wz0, wy * wz};
    float f0 = 0.f, f1 = 0.f;
#pragma unroll
    for (int j = 0; j < 4; ++j) {
        float w0 = wx0 * wyz[j], w1 = wx * wyz[j];
        f0 += w0 * vx0[j].x + w1 * vx1[j].x;
        f1 += w0 * vx0[j].y + w1 * vx1[j].y;
    }
    h2 r; r[0] = (_Float16)f0; r[1] = (_Float16)f1;
    return r;
}

// ---------------- Kernel A (phase 1): hash levels lbase.. -> enc2 [16][N] ----
// grid (4096, nLevels), y slow-varying -> 1-2 levels hot -> L2-resident tables.
__global__ __launch_bounds__(256) void encode_kernel(
    const float* __restrict__ xs, const h2* __restrict__ table,
    h2* __restrict__ enc2, Levels lv, int lbase, int N)
{
    __shared__ float sx[768];
    const int i0 = blockIdx.x * 256;
    for (int t = threadIdx.x; t < 768; t += 256) sx[t] = xs[(size_t)i0 * 3 + t];
    __syncthreads();

    const int l = lbase + blockIdx.y;
    const int i = i0 + threadIdx.x;
    if (i >= N) return;
    h2 r = encode_point(sx[threadIdx.x * 3], sx[threadIdx.x * 3 + 1],
                        sx[threadIdx.x * 3 + 2], lv.scale[l], lv.res[l],
                        (lv.dense_mask >> l) & 1u, table + (size_t)l * T_SIZE);
    enc2[(size_t)l * N + i] = r;       // coalesced 4B store
}

// generic 8-half fragment load (f16 direct dwordx4, or f32 + convert)
template <typename WT>
__device__ __forceinline__ h8 load_frag8(const WT* p) {
    if constexpr (sizeof(WT) == 2) {
        return *(const h8*)p;
    } else {
        h8 r;
#pragma unroll
        for (int j = 0; j < 8; ++j) r[j] = (_Float16)p[j];
        return r;
    }
}

// ------------- Kernel B (fused): encode levels {0-4,15} locally + MLP -------
// Small-table levels (3.3MB total, L2-resident at ANY ordering) are encoded
// per-block into wave-private LDS (never touch global enc2); 10 hash levels
// staged coalesced from enc2. Gather-bound encode overlaps MFMA/VALU MLP
// across resident blocks. sEnc(4KB/wave) unioned under sAct(9216B/wave);
// layer-1 B-frags pre-read to regs before sAct clobbers. One barrier total.
// A[m=lane&15][k=quad*8+j]; B[k=quad*8+j][n=lane&15]; D[row=quad*4+r][col=lane&15].
template <typename WT, bool LOCAL>
__global__ __launch_bounds__(256, 3) void fused_kernel(
    const float* __restrict__ xs, const h2* __restrict__ table16,
    const h2* __restrict__ enc2,
    const WT* __restrict__ w1, const WT* __restrict__ w2,
    const WT* __restrict__ w3, const float* __restrict__ w4,
    float* __restrict__ out, Levels lv, int N)
{
    constexpr int AR = 72;                          // 144B act rows, 16B-aligned
    __shared__ __align__(16) char smem[4 * 9216];   // per-wave: sEnc ∪ sAct
    __shared__ float sx[768];

    const int tid  = threadIdx.x;
    const int wave = tid >> 6;
    const int lane = tid & 63;
    const int lrow = lane & 15;
    const int quad = lane >> 4;
    const int base = blockIdx.x * 256;
    char* wmem = smem + wave * 9216;
    const f4 zero = {0.f, 0.f, 0.f, 0.f};

    for (int t = tid; t < 768; t += 256) sx[t] = xs[(size_t)base * 3 + t];
    __syncthreads();
    const float px = sx[tid * 3], py = sx[tid * 3 + 1], pz = sx[tid * 3 + 2];
    const int p = tid & 63;                         // local point in wave region

    // sEnc layout (transposed): byte = (l>>2)*1024 + p*16 + (l&3)*4  (2-way banks)
    if (LOCAL) {
#pragma unroll
        for (int l = 5; l < 15; ++l) {              // 10 coalesced 4B global loads
            h2 v = enc2[(size_t)l * N + base + tid];
            *(h2*)(wmem + ((l >> 2) << 10) + (p << 4) + ((l & 3) << 2)) = v;
        }
        const int LMAP[6] = {0, 1, 2, 3, 4, 15};    // tables sum 3.3MB: L2-safe
#pragma unroll 2
        for (int s6 = 0; s6 < 6; ++s6) {
            const int l = LMAP[s6];
            h2 v = encode_point(px, py, pz, lv.scale[l], lv.res[l],
                                (lv.dense_mask >> l) & 1u,
                                table16 + (size_t)l * T_SIZE);
            *(h2*)(wmem + ((l >> 2) << 10) + (p << 4) + ((l & 3) << 2)) = v;
        }
    } else {
#pragma unroll
        for (int l = 0; l < 16; ++l) {
            h2 v = enc2[(size_t)l * N + base + tid];
            *(h2*)(wmem + ((l >> 2) << 10) + (p << 4) + ((l & 3) << 2)) = v;
        }
    }

    asm volatile("" ::: "memory");   // keep weight loads after encode (pressure)

    // weight A-frags (L2-hot) + packed w4
    h8 aW1[4];
#pragma unroll
    for (int tm = 0; tm < 4; ++tm)
        aW1[tm] = load_frag8(w1 + (tm * 16 + lrow) * 32 + quad * 8);
    h8 aW2[4][2], aW3[4][2];
#pragma unroll
    for (int tm = 0; tm < 4; ++tm)
#pragma unroll
        for (int km = 0; km < 2; ++km) {
            aW2[tm][km] = load_frag8(w2 + (tm * 16 + lrow) * 64 + km * 32 + quad * 8);
            aW3[tm][km] = load_frag8(w3 + (tm * 16 + lrow) * 64 + km * 32 + quad * 8);
        }
    h4 w4q[4];
#pragma unroll
    for (int tm = 0; tm < 4; ++tm)
#pragma unroll
        for (int r = 0; r < 4; ++r) w4q[tm][r] = (_Float16)w4[tm * 16 + quad * 4 + r];

    // pre-read ALL layer-1 B-frags (wave-private rows; same-wave LDS ordering)
    // BEFORE sAct overwrites the sEnc region.
    h8 bin[4];
#pragma unroll
    for (int t = 0; t < 4; ++t)
        bin[t] = *(const h8*)(wmem + (quad << 10) + ((t * 16 + lrow) << 4));

    _Float16* wAct = (_Float16*)wmem;               // local rows 0..63, stride AR

    // ---- Layer 1: D1 = W1 · enc^T ----
#pragma unroll
    for (int t = 0; t < 4; ++t) {
        const int arow = (t * 16 + lrow) * AR;
#pragma unroll
        for (int tm = 0; tm < 4; ++tm) {
            f4 acc = __builtin_amdgcn_mfma_f32_16x16x32_f16(aW1[tm], bin[t], zero, 0, 0, 0);
            h4 pk;
#pragma unroll
            for (int r = 0; r < 4; ++r) pk[r] = (_Float16)softplus10(acc[r]);
            *(h4*)&wAct[arow + tm * 16 + quad * 4] = pk;
        }
    }

    // ---- Layer 2: D2 = W2 · act1^T ----
#pragma unroll
    for (int t = 0; t < 4; ++t) {
        const int arow = (t * 16 + lrow) * AR;
        h8 b0 = *(const h8*)&wAct[arow + quad * 8];
        h8 b1 = *(const h8*)&wAct[arow + 32 + quad * 8];
        f4 accs[4];
#pragma unroll
        for (int tm = 0; tm < 4; ++tm) {
            f4 acc = __builtin_amdgcn_mfma_f32_16x16x32_f16(aW2[tm][0], b0, zero, 0, 0, 0);
            acc     = __builtin_amdgcn_mfma_f32_16x16x32_f16(aW2[tm][1], b1, acc,  0, 0, 0);
            accs[tm] = acc;
        }
#pragma unroll
        for (int tm = 0; tm < 4; ++tm) {
            h4 pk;
#pragma unroll
            for (int r = 0; r < 4; ++r) pk[r] = (_Float16)softplus10(accs[tm][r]);
            *(h4*)&wAct[arow + tm * 16 + quad * 4] = pk;
        }
    }

    // ---- Layer 3+4 fused: sdf = w4 · softplus(W3 · act2^T) ----
#pragma unroll
    for (int t = 0; t < 4; ++t) {
        const int arow = (t * 16 + lrow) * AR;
        h8 b0 = *(const h8*)&wAct[arow + quad * 8];
        h8 b1 = *(const h8*)&wAct[arow + 32 + quad * 8];
        float sum = 0.f;
#pragma unroll
        for (int tm = 0; tm < 4; ++tm) {
            f4 acc = __builtin_amdgcn_mfma_f32_16x16x32_f16(aW3[tm][0], b0, zero, 0, 0, 0);
            acc     = __builtin_amdgcn_mfma_f32_16x16x32_f16(aW3[tm][1], b1, acc,  0, 0, 0);
#pragma unroll
            for (int r = 0; r < 4; ++r)
                sum += (float)w4q[tm][r] * softplus10(acc[r]);
        }
        sum += __shfl_xor(sum, 16, 64);
        sum += __shfl_xor(sum, 32, 64);
        if (quad == 0)
            out[base + wave * 64 + t * 16 + lrow] = sum;
    }
}

// Fallback encode (f32 table, all 16 levels) if workspace too small
__global__ __launch_bounds__(256) void encode_kernel_f32(
    const float* __restrict__ xs, const float2* __restrict__ table,
    h2* __restrict__ enc2, Levels lv, int N)
{
    const int i = blockIdx.x * 256 + threadIdx.x;
    const int l = blockIdx.y;
    if (i >= N) return;
    float px = xs[3 * i], py = xs[3 * i + 1], pz = xs[3 * i + 2];
    float s = lv.scale[l];
    int res = lv.res[l];
    float fx = px * s + 0.5f, fy = py * s + 0.5f, fz = pz * s + 0.5f;
    float gx = floorf(fx), gy = floorf(fy), gz = floorf(fz);
    float wx = fx - gx, wy = fy - gy, wz = fz - gz;
    int cx = (int)gx, cy = (int)gy, cz = (int)gz;
    unsigned idx[8];
    if ((lv.dense_mask >> l) & 1u) {
        int r1 = res - 1;
        int x0 = min(cx, r1), x1 = min(cx + 1, r1);
        int y0 = min(cy, r1), y1 = min(cy + 1, r1);
        int z0 = min(cz, r1), z1 = min(cz + 1, r1);
        int rr = res * res;
        idx[0] = x0 + y0 * res + z0 * rr; idx[1] = x0 + y0 * res + z1 * rr;
        idx[2] = x0 + y1 * res + z0 * rr; idx[3] = x0 + y1 * res + z1 * rr;
        idx[4] = x1 + y0 * res + z0 * rr; idx[5] = x1 + y0 * res + z1 * rr;
        idx[6] = x1 + y1 * res + z0 * rr; idx[7] = x1 + y1 * res + z1 * rr;
    } else {
        unsigned hx0 = (unsigned)cx, hx1 = (unsigned)(cx + 1);
        unsigned hy0 = (unsigned)cy * 2654435761u, hy1 = (unsigned)(cy + 1) * 2654435761u;
        unsigned hz0 = (unsigned)cz * 805459861u,  hz1 = (unsigned)(cz + 1) * 805459861u;
        idx[0] = (hx0^hy0^hz0) & (T_SIZE-1); idx[1] = (hx0^hy0^hz1) & (T_SIZE-1);
        idx[2] = (hx0^hy1^hz0) & (T_SIZE-1); idx[3] = (hx0^hy1^hz1) & (T_SIZE-1);
        idx[4] = (hx1^hy0^hz0) & (T_SIZE-1); idx[5] = (hx1^hy0^hz1) & (T_SIZE-1);
        idx[6] = (hx1^hy1^hz0) & (T_SIZE-1); idx[7] = (hx1^hy1^hz1) & (T_SIZE-1);
    }
    const float2* tl = table + (size_t)l * T_SIZE;
    float wx0 = 1.f - wx, wy0 = 1.f - wy, wz0 = 1.f - wz;
    float wcs[8] = {wx0*wy0*wz0, wx0*wy0*wz, wx0*wy*wz0, wx0*wy*wz,
                    wx*wy0*wz0,  wx*wy0*wz,  wx*wy*wz0,  wx*wy*wz};
    float f0 = 0.f, f1 = 0.f;
#pragma unroll
    for (int c = 0; c < 8; ++c) {
        float2 v = tl[idx[c]];
        f0 += wcs[c] * v.x; f1 += wcs[c] * v.y;
    }
    h2 r; r[0] = (_Float16)f0; r[1] = (_Float16)f1;
    enc2[(size_t)l * N + i] = r;
}

extern "C" void kernel_launch(void* const* d_in, const int* in_sizes, int n_in,
                              void* d_out, int out_size, void* d_ws, size_t ws_size,
                              hipStream_t stream) {
    const float* x     = (const float*)d_in[0];
    const float* table = (const float*)d_in[1];
    const float* w1    = (const float*)d_in[2];
    const float* w2    = (const float*)d_in[3];
    const float* w3    = (const float*)d_in[4];
    const float* w4    = (const float*)d_in[5];
    float* out = (float*)d_out;
    const int N = in_sizes[0] / 3;                 // 1<<20

    Levels lv;
    lv.dense_mask = 0;
    const double pls = exp2(log2(2048.0 / 16.0) / 15.0);
    const double lg  = log2(pls);
    for (int l = 0; l < 16; ++l) {
        double sc = exp2((double)l * lg) * 16.0 - 1.0;
        int res = (int)ceil(sc) + 1;
        lv.scale[l] = (float)sc;
        lv.res[l]   = res;
        if ((long long)res * res * res <= (long long)T_SIZE) lv.dense_mask |= (1u << l);
    }

    const size_t encBytes   = (size_t)16 * N * 4;        // 64 MB ([16][N] h2)
    const size_t tableBytes = (size_t)16 * T_SIZE * 4;   // 33.5 MB f16 table
    const size_t whBytes    = 32768;                     // 10240 f16 weights
    h2* enc2 = (h2*)d_ws;

    const int ptBlocks = (N + 255) / 256;                // 4096

    if (ws_size >= encBytes + tableBytes + whBytes) {
        h2* table16 = (h2*)((char*)d_ws + encBytes);
        _Float16* wh = (_Float16*)((char*)d_ws + encBytes + tableBytes);
        const int total4 = 16 * T_SIZE / 4;              // 2,097,152
        const int convBlocks = (total4 + 10240 + 255) / 256;
        hipLaunchKernelGGL(convert_kernel, dim3(convBlocks), dim3(256), 0, stream,
                           (const float2*)table, table16, total4, w1, w2, w3, wh);
        // phase 1: hash levels 5..14, level-major
        hipLaunchKernelGGL(encode_kernel, dim3(ptBlocks, 10), dim3(256), 0, stream,
                           x, (const h2*)table16, enc2, lv, 5, N);
        // phase 2: fused local-encode {0-4,15} + MLP
        hipLaunchKernelGGL((fused_kernel<_Float16, true>), dim3(ptBlocks), dim3(256),
                           0, stream, x, (const h2*)table16, (const h2*)enc2,
                           wh, wh + 2048, wh + 6144, w4, out, lv, N);
    } else {
        hipLaunchKernelGGL(encode_kernel_f32, dim3(ptBlocks, 16), dim3(256), 0, stream,
                           x, (const float2*)table, enc2, lv, N);
        hipLaunchKernelGGL((fused_kernel<float, false>), dim3(ptBlocks), dim3(256),
                           0, stream, x, (const h2*)nullptr, (const h2*)enc2,
                           w1, w2, w3, w4, out, lv, N);
    }
}